// Round 3
// baseline (335.644 us; speedup 1.0000x reference)
//
#include <hip/hip_runtime.h>

typedef __bf16 bf16;
typedef __bf16 bf16x8 __attribute__((ext_vector_type(8)));
typedef __bf16 bf16x4 __attribute__((ext_vector_type(4)));
typedef _Float16 f16x4 __attribute__((ext_vector_type(4)));
typedef float  f32x4  __attribute__((ext_vector_type(4)));

#define LOG2E 1.44269504088896340736f
#define SCQ (0.125f * LOG2E)

__device__ __forceinline__ void async16(const void* g, void* l) {
  __builtin_amdgcn_global_load_lds(
      (const __attribute__((address_space(1))) unsigned int*)g,
      (__attribute__((address_space(3))) unsigned int*)l, 16, 0, 0);
}

__device__ __forceinline__ f32x4 mfma_bf16(bf16x8 a, bf16x8 b, f32x4 c) {
  return __builtin_amdgcn_mfma_f32_16x16x32_bf16(a, b, c, 0, 0, 0);
}
__device__ __forceinline__ f32x4 mfma_f16k16(f16x4 a, f16x4 b, f32x4 c) {
  return __builtin_amdgcn_mfma_f32_16x16x16f16(a, b, c, 0, 0, 0);
}

// ---------------- fp32 -> bf16 convert, all 3 activations in one launch --------
__global__ __launch_bounds__(256) void cvt3(const float* __restrict__ q,
                                            const float* __restrict__ k,
                                            const float* __restrict__ v,
                                            bf16* __restrict__ out) {
  int z = blockIdx.y;
  const float* in = z == 0 ? q : (z == 1 ? k : v);
  bf16* o = out + (size_t)z * 8388608;
  int i = blockIdx.x * 256 + threadIdx.x;
  const float4* p = (const float4*)in;
  float4 a = p[i * 2], c = p[i * 2 + 1];
  bf16x8 r;
  r[0] = (bf16)a.x; r[1] = (bf16)a.y; r[2] = (bf16)a.z; r[3] = (bf16)a.w;
  r[4] = (bf16)c.x; r[5] = (bf16)c.y; r[6] = (bf16)c.z; r[7] = (bf16)c.w;
  ((bf16x8*)o)[i] = r;
}

// ---------------- weight transpose: W[k][n] f32 -> Wt[n][k] bf16 ----------------
__global__ __launch_bounds__(256) void wtrans(const float* __restrict__ W0,
                                              const float* __restrict__ W1,
                                              const float* __restrict__ W2,
                                              bf16* __restrict__ Wt) {
  const float* W = blockIdx.z == 0 ? W0 : (blockIdx.z == 1 ? W1 : W2);
  bf16* O = Wt + (size_t)blockIdx.z * (1024 * 1024);
  __shared__ float t[64 * 69];
  int tid = threadIdx.x;
  int k0 = blockIdx.x * 64, n0 = blockIdx.y * 64;
  int r0 = tid >> 4, c0 = (tid & 15) * 4;
#pragma unroll
  for (int rr = 0; rr < 4; rr++) {
    int k = r0 + rr * 16;
    float4 v = *(const float4*)(W + (k0 + k) * 1024 + n0 + c0);
    t[k * 69 + c0 + 0] = v.x; t[k * 69 + c0 + 1] = v.y;
    t[k * 69 + c0 + 2] = v.z; t[k * 69 + c0 + 3] = v.w;
  }
  __syncthreads();
#pragma unroll
  for (int rr = 0; rr < 4; rr++) {
    int n = r0 + rr * 16;
    bf16x4 o;
#pragma unroll
    for (int j = 0; j < 4; j++) o[j] = (bf16)t[(c0 + j) * 69 + n];
    *(bf16x4*)(O + (n0 + n) * 1024 + k0 + c0) = o;
  }
}

// ---------------- batched projection GEMM (Q,K,V in one launch) ----------------
// z=0: qo = (A0*Wq + bq)*SCQ   bf16 natural [m][n]
// z=1: ko =  A1*Wk + bk        bf16 natural [m][n]
// z=2: vf =  A2*Wv + bv        f16, PV-fragment order
//      vf[b][h][kvb][t*4+dt][lane][4] ; element (kv, d):
//      kvb=kv>>6, t=(kv>>4)&3, lane=((kv>>2)&3)*16 + (d&15), j=kv&3, dt=d>>4
__global__ __launch_bounds__(256) void gemm_qkv(const bf16* __restrict__ Act,
                                                const bf16* __restrict__ Wt,
                                                const float* __restrict__ b0,
                                                const float* __restrict__ b1,
                                                const float* __restrict__ b2,
                                                bf16* __restrict__ qo,
                                                bf16* __restrict__ ko,
                                                _Float16* __restrict__ vf) {
  __shared__ bf16 smem[16384];          // sA 8192 | sB 8192  (32 KB)
  bf16* sA = smem;
  bf16* sB = smem + 8192;
  const int tid = threadIdx.x;
  const int wave = tid >> 6, lane = tid & 63;
  const int quad = lane >> 4, l15 = lane & 15;
  const int z = blockIdx.z;
  const int m0 = blockIdx.x * 128, n0 = blockIdx.y * 128;
  const bf16* A = Act + (size_t)z * 8388608;
  const bf16* Bt = Wt + (size_t)z * 1048576;
  const float* bias = z == 0 ? b0 : (z == 1 ? b1 : b2);

  const bf16* ap[4]; const bf16* bp[4]; int lo[4];
#pragma unroll
  for (int i = 0; i < 4; i++) {
    int g = wave * 256 + i * 64 + lane;
    int row = g >> 3, jl = (g & 7) ^ (row & 7);
    ap[i] = A + (m0 + row) * 1024 + jl * 8;
    bp[i] = Bt + (n0 + row) * 1024 + jl * 8;
    lo[i] = (wave * 256 + i * 64) * 8;
  }
  const int wm = (wave & 1) * 64, wn = (wave >> 1) * 64;
  f32x4 acc[4][4] = {};

  for (int kt = 0; kt < 16; kt++) {
    const int ko_ = kt * 64;
#pragma unroll
    for (int i = 0; i < 4; i++) async16(ap[i] + ko_, sA + lo[i]);
#pragma unroll
    for (int i = 0; i < 4; i++) async16(bp[i] + ko_, sB + lo[i]);
    __syncthreads();
#pragma unroll
    for (int ks = 0; ks < 2; ks++) {
      bf16x8 af[4], bv[4];
#pragma unroll
      for (int mt = 0; mt < 4; mt++) {
        int m = wm + mt * 16 + l15;
        int ph = (ks * 4 + quad) ^ (m & 7);
        af[mt] = *(const bf16x8*)(sA + m * 64 + ph * 8);
      }
#pragma unroll
      for (int nt = 0; nt < 4; nt++) {
        int n = wn + nt * 16 + l15;
        int ph = (ks * 4 + quad) ^ (n & 7);
        bv[nt] = *(const bf16x8*)(sB + n * 64 + ph * 8);
      }
#pragma unroll
      for (int mt = 0; mt < 4; mt++)
#pragma unroll
        for (int nt = 0; nt < 4; nt++)
          acc[mt][nt] = mfma_bf16(af[mt], bv[nt], acc[mt][nt]);
    }
    __syncthreads();
  }

  if (z != 2) {
    bf16* O = z == 0 ? qo : ko;
    const float sc = z == 0 ? SCQ : 1.0f;
#pragma unroll
    for (int nt = 0; nt < 4; nt++) {
      int n = n0 + wn + nt * 16 + l15;
      float bc = bias[n];
#pragma unroll
      for (int mt = 0; mt < 4; mt++)
#pragma unroll
        for (int r = 0; r < 4; r++) {
          int m = m0 + wm + mt * 16 + quad * 4 + r;
          O[m * 1024 + n] = (bf16)((acc[mt][nt][r] + bc) * sc);
        }
    }
  } else {
    // direct fragment-order stores: this thread's acc[mt][nt] IS one f16x4 frag
    const int b = m0 >> 11, s0 = m0 & 2047;
    const int kvb = (s0 + wm) >> 6;          // t = mt, j = r, kv-quad = quad
#pragma unroll
    for (int nt = 0; nt < 4; nt++) {
      int nn = n0 + wn + nt * 16;            // multiple of 16
      int h = nn >> 6, dt = (nn >> 4) & 3;
      float bc = bias[nn + l15];
#pragma unroll
      for (int mt = 0; mt < 4; mt++) {
        f16x4 pk;
#pragma unroll
        for (int r = 0; r < 4; r++) pk[r] = (_Float16)(acc[mt][nt][r] + bc);
        size_t off = ((((size_t)(b * 16 + h) * 32 + kvb) * 16 + (mt * 4 + dt)) * 64 + lane) * 4;
        *(f16x4*)(vf + off) = pk;
      }
    }
  }
}

// ---------------- flash attention, S^T trick, dbuf K/V ----------------
// Q pre-scaled bf16 [B,S,1024]; K bf16 [B,S,1024]; VF f16 fragment-order;
// Out fp32 [B,S,1024]. Q-tile 128 (wave owns 32 q), KV-tile 64.
__global__ __launch_bounds__(256) void attn(const bf16* __restrict__ Q,
                                            const bf16* __restrict__ K,
                                            const _Float16* __restrict__ VF,
                                            float* __restrict__ Out) {
  __shared__ bf16 sQ[8192];            // 128 x 64 (swizzled)
  __shared__ bf16 sK[2][4096];         // 64 x 64 (swizzled), double-buffered
  __shared__ _Float16 sV[2][4096];     // fragment-order, double-buffered
  const int tid = threadIdx.x;
  const int wave = tid >> 6, lane = tid & 63;
  const int quad = lane >> 4, l15 = lane & 15;
  const int q0 = blockIdx.x * 128, h = blockIdx.y, b = blockIdx.z;
  const bf16* Kbase = K + (size_t)(b * 2048) * 1024 + h * 64;
  const _Float16* Vbase = VF + (size_t)(b * 16 + h) * 131072;

  // stage Q (once) + K/V block 0
#pragma unroll
  for (int i = 0; i < 4; i++) {
    int g = i * 256 + tid;
    int row = g >> 3, jl = (g & 7) ^ (row & 7);
    async16(Q + (size_t)(b * 2048 + q0 + row) * 1024 + h * 64 + jl * 8, sQ + g * 8);
  }
#pragma unroll
  for (int i = 0; i < 2; i++) {
    int g = i * 256 + tid;
    int row = g >> 3, jl = (g & 7) ^ (row & 7);
    async16(Kbase + row * 1024 + jl * 8, sK[0] + g * 8);
    async16(Vbase + g * 8, sV[0] + g * 8);
  }
  __syncthreads();

  // Q fragments (B-operand: lane=q, k=quad*8+j), wave owns q rows wave*32..+31
  bf16x8 qf[2][2];
#pragma unroll
  for (int qt2 = 0; qt2 < 2; qt2++)
#pragma unroll
    for (int ks = 0; ks < 2; ks++) {
      int m = wave * 32 + qt2 * 16 + l15;
      int ph = (ks * 4 + quad) ^ (l15 & 7);
      qf[qt2][ks] = *(const bf16x8*)(sQ + m * 64 + ph * 8);
    }

  f32x4 oaccT[2][4] = {};    // [qt2][dt] : O^T tile, row=d(quad*4+r), col=q(l15)
  float ls[2] = {0.f, 0.f};

  const int ph0 = quad ^ (l15 & 7), ph1 = (4 + quad) ^ (l15 & 7);

  for (int kvb = 0; kvb < 32; kvb++) {
    const int cur = kvb & 1;
    // prefetch next K/V block BEFORE compute (barrier drain overlaps compute)
    if (kvb < 31) {
      int kn = (kvb + 1) * 64;
#pragma unroll
      for (int i = 0; i < 2; i++) {
        int g = i * 256 + tid;
        int row = g >> 3, jl = (g & 7) ^ (row & 7);
        async16(Kbase + (size_t)(kn + row) * 1024 + jl * 8, sK[cur ^ 1] + g * 8);
        async16(Vbase + (kvb + 1) * 4096 + g * 8, sV[cur ^ 1] + g * 8);
      }
    }
    const bf16* sKc = sK[cur];
    const _Float16* sVc = sV[cur];
#pragma unroll
    for (int t = 0; t < 4; t++) {
      int row = t * 16 + l15;
      bf16x8 kf0 = *(const bf16x8*)(sKc + row * 64 + ph0 * 8);
      bf16x8 kf1 = *(const bf16x8*)(sKc + row * 64 + ph1 * 8);
      f32x4 st0 = {}, st1 = {};
      st0 = mfma_bf16(kf0, qf[0][0], st0);
      st0 = mfma_bf16(kf1, qf[0][1], st0);
      st1 = mfma_bf16(kf0, qf[1][0], st1);
      st1 = mfma_bf16(kf1, qf[1][1], st1);
      f16x4 pf0, pf1;
#pragma unroll
      for (int r = 0; r < 4; r++) {
        float p0 = __builtin_amdgcn_exp2f(st0[r]);
        float p1 = __builtin_amdgcn_exp2f(st1[r]);
        ls[0] += p0; ls[1] += p1;
        pf0[r] = (_Float16)p0; pf1[r] = (_Float16)p1;
      }
#pragma unroll
      for (int dt = 0; dt < 4; dt++) {
        f16x4 va = *(const f16x4*)(sVc + ((t * 4 + dt) * 64 + lane) * 4);
        oaccT[0][dt] = mfma_f16k16(va, pf0, oaccT[0][dt]);
        oaccT[1][dt] = mfma_f16k16(va, pf1, oaccT[1][dt]);
      }
    }
    __syncthreads();
  }

  // ---- epilogue: reduce l across quads, scale, store fp32 ----
#pragma unroll
  for (int qt2 = 0; qt2 < 2; qt2++) {
    float l = ls[qt2];
    l += __shfl_xor(l, 16);
    l += __shfl_xor(l, 32);
    float inv = 1.f / l;
    int qrow = b * 2048 + q0 + wave * 32 + qt2 * 16 + l15;
#pragma unroll
    for (int dt = 0; dt < 4; dt++) {
      float4 v;
      v.x = oaccT[qt2][dt][0] * inv;
      v.y = oaccT[qt2][dt][1] * inv;
      v.z = oaccT[qt2][dt][2] * inv;
      v.w = oaccT[qt2][dt][3] * inv;
      *(float4*)(Out + (size_t)qrow * 1024 + h * 64 + dt * 16 + quad * 4) = v;
    }
  }
}

extern "C" void kernel_launch(void* const* d_in, const int* in_sizes, int n_in,
                              void* d_out, int out_size, void* d_ws, size_t ws_size,
                              hipStream_t stream) {
  const float* key   = (const float*)d_in[0];
  const float* value = (const float*)d_in[1];
  const float* query = (const float*)d_in[2];
  const float* Wq = (const float*)d_in[3];
  const float* bq = (const float*)d_in[4];
  const float* Wk = (const float*)d_in[5];
  const float* bk = (const float*)d_in[6];
  const float* Wv = (const float*)d_in[7];
  const float* bv = (const float*)d_in[8];
  float* out = (float*)d_out;

  char* ws = (char*)d_ws;
  bf16* actb   = (bf16*)(ws);                       // 48 MB: [query|key|value] bf16
  bf16* wt     = (bf16*)(ws + 50331648);            // 6 MB: Wq^T,Wk^T,Wv^T
  bf16* qo     = (bf16*)(ws + 56623104);            // 16 MB (pre-scaled)
  bf16* ko     = (bf16*)(ws + 73400320);            // 16 MB
  _Float16* vf = (_Float16*)(ws + 90177536);        // 16 MB fragment-order
  (void)in_sizes; (void)n_in; (void)out_size; (void)ws_size;

  wtrans<<<dim3(16, 16, 3), 256, 0, stream>>>(Wq, Wk, Wv, wt);
  cvt3<<<dim3(4096, 3), 256, 0, stream>>>(query, key, value, actb);
  gemm_qkv<<<dim3(64, 8, 3), 256, 0, stream>>>(actb, wt, bq, bk, bv, qo, ko, vf);
  attn<<<dim3(16, 16, 4), 256, 0, stream>>>(qo, ko, vf, out);
}

// Round 4
// 314.042 us; speedup vs baseline: 1.0688x; 1.0688x over previous
//
#include <hip/hip_runtime.h>

typedef __bf16 bf16;
typedef __bf16 bf16x8 __attribute__((ext_vector_type(8)));
typedef __bf16 bf16x4 __attribute__((ext_vector_type(4)));
typedef _Float16 f16x4 __attribute__((ext_vector_type(4)));
typedef float  f32x4  __attribute__((ext_vector_type(4)));

#define LOG2E 1.44269504088896340736f
#define SCQ (0.125f * LOG2E)

__device__ __forceinline__ void async16(const void* g, void* l) {
  __builtin_amdgcn_global_load_lds(
      (const __attribute__((address_space(1))) unsigned int*)g,
      (__attribute__((address_space(3))) unsigned int*)l, 16, 0, 0);
}

__device__ __forceinline__ f32x4 mfma_bf16(bf16x8 a, bf16x8 b, f32x4 c) {
  return __builtin_amdgcn_mfma_f32_16x16x32_bf16(a, b, c, 0, 0, 0);
}
__device__ __forceinline__ f32x4 mfma_f16k16(f16x4 a, f16x4 b, f32x4 c) {
  return __builtin_amdgcn_mfma_f32_16x16x16f16(a, b, c, 0, 0, 0);
}

// ---------------- fp32 -> bf16 convert, all 3 activations in one launch --------
__global__ __launch_bounds__(256) void cvt3(const float* __restrict__ q,
                                            const float* __restrict__ k,
                                            const float* __restrict__ v,
                                            bf16* __restrict__ out) {
  int z = blockIdx.y;
  const float* in = z == 0 ? q : (z == 1 ? k : v);
  bf16* o = out + (size_t)z * 8388608;
  int i = blockIdx.x * 256 + threadIdx.x;
  const float4* p = (const float4*)in;
  float4 a = p[i * 2], c = p[i * 2 + 1];
  bf16x8 r;
  r[0] = (bf16)a.x; r[1] = (bf16)a.y; r[2] = (bf16)a.z; r[3] = (bf16)a.w;
  r[4] = (bf16)c.x; r[5] = (bf16)c.y; r[6] = (bf16)c.z; r[7] = (bf16)c.w;
  ((bf16x8*)o)[i] = r;
}

// ---------------- weight transpose: W[k][n] f32 -> Wt[n][k] bf16 ----------------
__global__ __launch_bounds__(256) void wtrans(const float* __restrict__ W0,
                                              const float* __restrict__ W1,
                                              const float* __restrict__ W2,
                                              bf16* __restrict__ Wt) {
  const float* W = blockIdx.z == 0 ? W0 : (blockIdx.z == 1 ? W1 : W2);
  bf16* O = Wt + (size_t)blockIdx.z * (1024 * 1024);
  __shared__ float t[64 * 69];
  int tid = threadIdx.x;
  int k0 = blockIdx.x * 64, n0 = blockIdx.y * 64;
  int r0 = tid >> 4, c0 = (tid & 15) * 4;
#pragma unroll
  for (int rr = 0; rr < 4; rr++) {
    int k = r0 + rr * 16;
    float4 v = *(const float4*)(W + (k0 + k) * 1024 + n0 + c0);
    t[k * 69 + c0 + 0] = v.x; t[k * 69 + c0 + 1] = v.y;
    t[k * 69 + c0 + 2] = v.z; t[k * 69 + c0 + 3] = v.w;
  }
  __syncthreads();
#pragma unroll
  for (int rr = 0; rr < 4; rr++) {
    int n = r0 + rr * 16;
    bf16x4 o;
#pragma unroll
    for (int j = 0; j < 4; j++) o[j] = (bf16)t[(c0 + j) * 69 + n];
    *(bf16x4*)(O + (n0 + n) * 1024 + k0 + c0) = o;
  }
}

// ---------------- batched projection GEMM, tile 128x256 ----------------
// grid (64, 4, 3); in-z linear index XCD-swizzled so the 4 blocks sharing an
// A-tile (same m, different n) sit stride-8 apart -> same XCD under round-robin.
// z=0: qo = (A*Wq+bq)*SCQ bf16 [m][n]; z=1: ko = A*Wk+bk bf16 [m][n];
// z=2: vf = A*Wv+bv f16 in PV-fragment order.
__global__ __launch_bounds__(256, 2) void gemm_qkv(const bf16* __restrict__ Act,
                                                   const bf16* __restrict__ Wt,
                                                   const float* __restrict__ b0,
                                                   const float* __restrict__ b1,
                                                   const float* __restrict__ b2,
                                                   bf16* __restrict__ qo,
                                                   bf16* __restrict__ ko,
                                                   _Float16* __restrict__ vf) {
  __shared__ bf16 smem[24576];          // sA 128x64 (16KB) | sB 256x64 (32KB)
  bf16* sA = smem;
  bf16* sB = smem + 8192;
  const int tid = threadIdx.x;
  const int wave = tid >> 6, lane = tid & 63;
  const int quad = lane >> 4, l15 = lane & 15;
  const int z = blockIdx.z;
  const int lin = blockIdx.y * 64 + blockIdx.x;     // 0..255 within z
  const int tx = (lin & 7) | ((lin >> 5) << 3);     // 0..63  (m-block)
  const int ty = (lin >> 3) & 3;                    // 0..3   (n-block)
  const int m0 = tx * 128, n0 = ty * 256;
  const bf16* A = Act + (size_t)z * 8388608;
  const bf16* Bt = Wt + (size_t)z * 1048576;
  const float* bias = z == 0 ? b0 : (z == 1 ? b1 : b2);

  const bf16* ap[4]; int loa[4];
  const bf16* bp[8]; int lob[8];
#pragma unroll
  for (int i = 0; i < 4; i++) {
    int g = wave * 256 + i * 64 + lane;
    int row = g >> 3, jl = (g & 7) ^ (row & 7);
    ap[i] = A + (m0 + row) * 1024 + jl * 8;
    loa[i] = (wave * 256 + i * 64) * 8;
  }
#pragma unroll
  for (int i = 0; i < 8; i++) {
    int g = wave * 512 + i * 64 + lane;
    int row = g >> 3, jl = (g & 7) ^ (row & 7);
    bp[i] = Bt + (n0 + row) * 1024 + jl * 8;
    lob[i] = (wave * 512 + i * 64) * 8;
  }
  const int wm = (wave & 1) * 64, wn = (wave >> 1) * 128;
  f32x4 acc[4][8] = {};

  for (int kt = 0; kt < 16; kt++) {
    const int ko_ = kt * 64;
#pragma unroll
    for (int i = 0; i < 4; i++) async16(ap[i] + ko_, sA + loa[i]);
#pragma unroll
    for (int i = 0; i < 8; i++) async16(bp[i] + ko_, sB + lob[i]);
    __syncthreads();
#pragma unroll
    for (int ks = 0; ks < 2; ks++) {
      bf16x8 af[4];
#pragma unroll
      for (int mt = 0; mt < 4; mt++) {
        int m = wm + mt * 16 + l15;
        int ph = (ks * 4 + quad) ^ (m & 7);
        af[mt] = *(const bf16x8*)(sA + m * 64 + ph * 8);
      }
#pragma unroll
      for (int nh = 0; nh < 2; nh++) {
        bf16x8 bv[4];
#pragma unroll
        for (int nt = 0; nt < 4; nt++) {
          int n = wn + (nh * 4 + nt) * 16 + l15;
          int ph = (ks * 4 + quad) ^ (n & 7);
          bv[nt] = *(const bf16x8*)(sB + n * 64 + ph * 8);
        }
#pragma unroll
        for (int mt = 0; mt < 4; mt++)
#pragma unroll
          for (int nt = 0; nt < 4; nt++)
            acc[mt][nh * 4 + nt] = mfma_bf16(af[mt], bv[nt], acc[mt][nh * 4 + nt]);
      }
    }
    __syncthreads();
  }

  if (z != 2) {
    bf16* O = z == 0 ? qo : ko;
    const float sc = z == 0 ? SCQ : 1.0f;
#pragma unroll
    for (int nt = 0; nt < 8; nt++) {
      int n = n0 + wn + nt * 16 + l15;
      float bc = bias[n];
#pragma unroll
      for (int mt = 0; mt < 4; mt++)
#pragma unroll
        for (int r = 0; r < 4; r++) {
          int m = m0 + wm + mt * 16 + quad * 4 + r;
          O[m * 1024 + n] = (bf16)((acc[mt][nt][r] + bc) * sc);
        }
    }
  } else {
    // fragment-order stores: acc[mt][nt] IS one PV A-operand f16x4 fragment
    const int b = m0 >> 11, s0 = m0 & 2047;
    const int kvb = (s0 + wm) >> 6;          // t = mt, j = r, kv-quad = quad
#pragma unroll
    for (int nt = 0; nt < 8; nt++) {
      int nn = n0 + wn + nt * 16;            // multiple of 16
      int h = nn >> 6, dt = (nn >> 4) & 3;
      float bc = bias[nn + l15];
#pragma unroll
      for (int mt = 0; mt < 4; mt++) {
        f16x4 pk;
#pragma unroll
        for (int r = 0; r < 4; r++) pk[r] = (_Float16)(acc[mt][nt][r] + bc);
        size_t off = ((((size_t)(b * 16 + h) * 32 + kvb) * 16 + (mt * 4 + dt)) * 64 + lane) * 4;
        *(f16x4*)(vf + off) = pk;
      }
    }
  }
}

// ---------------- flash attention, S^T trick, KV-tile 128, single-buffer -------
// Q pre-scaled bf16 [B,S,1024]; K bf16 [B,S,1024]; VF f16 fragment-order;
// Out fp32 [B,S,1024]. Q-tile 128 (wave owns 32 q).
__global__ __launch_bounds__(256, 4) void attn(const bf16* __restrict__ Q,
                                               const bf16* __restrict__ K,
                                               const _Float16* __restrict__ VF,
                                               float* __restrict__ Out) {
  __shared__ bf16 sQ[8192];        // 128 x 64 (16 KB)
  __shared__ bf16 sK[8192];        // 128 x 64 (16 KB)
  __shared__ _Float16 sV[8192];    // 2 x [16][64][4] fragment-order (16 KB)
  const int tid = threadIdx.x;
  const int wave = tid >> 6, lane = tid & 63;
  const int quad = lane >> 4, l15 = lane & 15;
  const int q0 = blockIdx.x * 128, h = blockIdx.y, b = blockIdx.z;
  const bf16* Kbase = K + (size_t)(b * 2048) * 1024 + h * 64;
  const _Float16* Vbase = VF + (size_t)(b * 16 + h) * 131072;

  // stage Q + K/V block 0
#pragma unroll
  for (int i = 0; i < 4; i++) {
    int g = i * 256 + tid;
    int row = g >> 3, jl = (g & 7) ^ (row & 7);
    async16(Q + (size_t)(b * 2048 + q0 + row) * 1024 + h * 64 + jl * 8, sQ + g * 8);
    async16(Kbase + (size_t)row * 1024 + jl * 8, sK + g * 8);
    async16(Vbase + g * 8, sV + g * 8);
  }
  __syncthreads();

  // Q fragments (B-operand: lane=q, k=quad*8+j), wave owns q rows wave*32..+31
  bf16x8 qf[2][2];
#pragma unroll
  for (int qt2 = 0; qt2 < 2; qt2++)
#pragma unroll
    for (int ks = 0; ks < 2; ks++) {
      int m = wave * 32 + qt2 * 16 + l15;
      int ph = (ks * 4 + quad) ^ (l15 & 7);
      qf[qt2][ks] = *(const bf16x8*)(sQ + m * 64 + ph * 8);
    }

  f32x4 oaccT[2][4] = {};    // [qt2][dt] : O^T tile, row=d(quad*4+r), col=q(l15)
  float ls[2] = {0.f, 0.f};
  const int ph0 = quad ^ (l15 & 7), ph1 = (4 + quad) ^ (l15 & 7);

  for (int kvb = 0; kvb < 16; kvb++) {
#pragma unroll
    for (int t = 0; t < 8; t++) {
      int row = t * 16 + l15;
      bf16x8 kf0 = *(const bf16x8*)(sK + row * 64 + ph0 * 8);
      bf16x8 kf1 = *(const bf16x8*)(sK + row * 64 + ph1 * 8);
      f32x4 st0 = {}, st1 = {};
      st0 = mfma_bf16(kf0, qf[0][0], st0);
      st0 = mfma_bf16(kf1, qf[0][1], st0);
      st1 = mfma_bf16(kf0, qf[1][0], st1);
      st1 = mfma_bf16(kf1, qf[1][1], st1);
      f16x4 pf0, pf1;
#pragma unroll
      for (int r = 0; r < 4; r++) {
        float p0 = __builtin_amdgcn_exp2f(st0[r]);
        float p1 = __builtin_amdgcn_exp2f(st1[r]);
        ls[0] += p0; ls[1] += p1;
        pf0[r] = (_Float16)p0; pf1[r] = (_Float16)p1;
      }
      const _Float16* sVt = sV + (t >> 2) * 4096;
      int tl = (t & 3) * 4;
#pragma unroll
      for (int dt = 0; dt < 4; dt++) {
        f16x4 va = *(const f16x4*)(sVt + ((tl + dt) * 64 + lane) * 4);
        oaccT[0][dt] = mfma_f16k16(va, pf0, oaccT[0][dt]);
        oaccT[1][dt] = mfma_f16k16(va, pf1, oaccT[1][dt]);
      }
    }
    __syncthreads();
    if (kvb < 15) {
      int kn = (kvb + 1) * 128;
#pragma unroll
      for (int i = 0; i < 4; i++) {
        int g = i * 256 + tid;
        int row = g >> 3, jl = (g & 7) ^ (row & 7);
        async16(Kbase + (size_t)(kn + row) * 1024 + jl * 8, sK + g * 8);
        async16(Vbase + (kvb + 1) * 8192 + g * 8, sV + g * 8);
      }
      __syncthreads();
    }
  }

  // ---- epilogue: reduce l across quads, scale, store fp32 ----
#pragma unroll
  for (int qt2 = 0; qt2 < 2; qt2++) {
    float l = ls[qt2];
    l += __shfl_xor(l, 16);
    l += __shfl_xor(l, 32);
    float inv = 1.f / l;
    int qrow = b * 2048 + q0 + wave * 32 + qt2 * 16 + l15;
#pragma unroll
    for (int dt = 0; dt < 4; dt++) {
      float4 v;
      v.x = oaccT[qt2][dt][0] * inv;
      v.y = oaccT[qt2][dt][1] * inv;
      v.z = oaccT[qt2][dt][2] * inv;
      v.w = oaccT[qt2][dt][3] * inv;
      *(float4*)(Out + (size_t)qrow * 1024 + h * 64 + dt * 16 + quad * 4) = v;
    }
  }
}

extern "C" void kernel_launch(void* const* d_in, const int* in_sizes, int n_in,
                              void* d_out, int out_size, void* d_ws, size_t ws_size,
                              hipStream_t stream) {
  const float* key   = (const float*)d_in[0];
  const float* value = (const float*)d_in[1];
  const float* query = (const float*)d_in[2];
  const float* Wq = (const float*)d_in[3];
  const float* bq = (const float*)d_in[4];
  const float* Wk = (const float*)d_in[5];
  const float* bk = (const float*)d_in[6];
  const float* Wv = (const float*)d_in[7];
  const float* bv = (const float*)d_in[8];
  float* out = (float*)d_out;

  char* ws = (char*)d_ws;
  bf16* actb   = (bf16*)(ws);                       // 48 MB: [query|key|value] bf16
  bf16* wt     = (bf16*)(ws + 50331648);            // 6 MB: Wq^T,Wk^T,Wv^T
  bf16* qo     = (bf16*)(ws + 56623104);            // 16 MB (pre-scaled)
  bf16* ko     = (bf16*)(ws + 73400320);            // 16 MB
  _Float16* vf = (_Float16*)(ws + 90177536);        // 16 MB fragment-order
  (void)in_sizes; (void)n_in; (void)out_size; (void)ws_size;

  wtrans<<<dim3(16, 16, 3), 256, 0, stream>>>(Wq, Wk, Wv, wt);
  cvt3<<<dim3(4096, 3), 256, 0, stream>>>(query, key, value, actb);
  gemm_qkv<<<dim3(64, 4, 3), 256, 0, stream>>>(actb, wt, bq, bk, bv, qo, ko, vf);
  attn<<<dim3(16, 16, 4), 256, 0, stream>>>(qo, ko, vf, out);
}